// Round 7
// baseline (609.805 us; speedup 1.0000x reference)
//
#include <hip/hip_runtime.h>

#define M 64
#define FG_T 0.6f
#define BG_T 0.4f

// packed column entry: (iou_bits << 32) | ~n — iou in (0,1] so the bit pattern
// is monotone; ties in iou resolve to SMALLER n (first occurrence = np argmax).
// 0 = "no entry"; fixup decodes p==0 -> anchor 0 (np argmax of an all-zero col).

__device__ inline float readlane_f(float v, int lane) {
    return __uint_as_float(__builtin_amdgcn_readlane(__float_as_uint(v), (unsigned)lane));
}

// -------- lb kernel: per-(b,m) lower bound on the column max + ws init ------
// For GT m, evaluate the EXACT iou (same op order as everywhere) of the 54 db
// anchors at the grid cell nearest the GT center (6 levels x 9 shapes). Each is
// a real anchor's iou -> max over them is a guaranteed lower bound on the
// column max. Also zero-inits col[b] and the per-batch done-counter.
__global__ __launch_bounds__(64) void lb_kernel(
    const float* __restrict__ gt,    // [B, M, 4] xyxy
    const float* __restrict__ db,    // [N, 4] xywh
    float* __restrict__ lb,          // [B, M]
    unsigned long long* __restrict__ col,  // [B, M] — zero-initialized here
    int* __restrict__ counter)       // [B] — zero-initialized here
{
#pragma clang fp contract(off)
    const int b = blockIdx.x;
    const int m = threadIdx.x;

    col[b * M + m] = 0ull;
    if (m == 0) counter[b] = 0;

    const float4 g = ((const float4*)gt)[b * M + m];
    const float area_g = (g.z - g.x) * (g.w - g.y);   // reference op order
    const float gcx = (g.x + g.z) * 0.5f;
    const float gcy = (g.y + g.w) * 0.5f;

    const int   fms[6]  = {64, 32, 16, 8, 4, 2};
    const float stp[6]  = {8.0f, 16.0f, 32.0f, 64.0f, 128.0f, 256.0f};
    const int   off[6]  = {0, 36864, 46080, 48384, 48960, 49104};

    float best = 0.0f;
    #pragma unroll
    for (int i = 0; i < 6; ++i) {
        int fx = fms[i];
        int x = (int)(gcx / stp[i]); x = min(max(x, 0), fx - 1);
        int y = (int)(gcy / stp[i]); y = min(max(y, 0), fx - 1);
        int base = off[i] + (y * fx + x) * 9;
        for (int a = 0; a < 9; ++a) {
            float4 d = ((const float4*)db)[base + a];
            float ax0 = d.x - d.z / 2.0f;
            float ay0 = d.y - d.w / 2.0f;
            float ax1 = d.x + d.z / 2.0f;
            float ay1 = d.y + d.w / 2.0f;
            float area_a = (ax1 - ax0) * (ay1 - ay0);
            float ltx = fmaxf(ax0, g.x);
            float lty = fmaxf(ay0, g.y);
            float rbx = fminf(ax1, g.z);
            float rby = fminf(ay1, g.w);
            float w = fmaxf(rbx - ltx, 0.0f);
            float h = fmaxf(rby - lty, 0.0f);
            float inter = w * h;
            float iou = inter / ((area_a + area_g) - inter);  // exact anchor iou
            best = fmaxf(best, iou);
        }
    }
    lb[b * M + m] = best;
}

// ------- row kernel: per-anchor best GT + column candidates + fused fixup -------
__global__ __launch_bounds__(256) void row_kernel(
    const float* __restrict__ gt,    // [B, M, 4] xyxy
    const int*   __restrict__ lab,   // [B, M]
    const float* __restrict__ db,    // [N, 4] xywh
    const float* __restrict__ lb,    // [B, M] column-max lower bound
    float* __restrict__ out_loc,     // [B, N, 4]
    float* __restrict__ out_cls,     // [B, N]
    unsigned long long* __restrict__ col,  // [B, M] packed column max
    int* __restrict__ counter,       // [B] done-block counter
    int N)
{
#pragma clang fp contract(off)
    __shared__ int s_a[M];
    __shared__ int s_last;

    const int b   = blockIdx.y;
    const int tid = threadIdx.x;
    const float4* __restrict__ gtb = (const float4*)gt + b * M;

    // Reverse chunk order: coarse-level anchors (high n) have whole-image wave
    // bboxes (mask ~ all 64 GTs, 5-10x work) — dispatch them FIRST so the drain
    // tail is made of many cheap level-0 blocks, not a few heavy ones.
    const int  chunk = gridDim.x - 1 - blockIdx.x;
    const int  n     = chunk * 256 + tid;
    const bool valid = (n < N);
    const int  nl    = valid ? n : (N - 1);

    const float4 d = ((const float4*)db)[nl];
    // db_xyxy exactly as reference: c - wh/2, c + wh/2 (div by 2 is exact)
    const float ax0 = d.x - d.z / 2.0f;
    const float ay0 = d.y - d.w / 2.0f;
    const float ax1 = d.x + d.z / 2.0f;
    const float ay1 = d.y + d.w / 2.0f;
    const float area_a = (ax1 - ax0) * (ay1 - ay0);

    // one-time wave bbox (union of the wave's 64 anchors)
    float wx0 = ax0, wy0 = ay0, wx1 = ax1, wy1 = ay1;
    #pragma unroll
    for (int off = 1; off < 64; off <<= 1) {
        wx0 = fminf(wx0, __shfl_xor(wx0, off));
        wy0 = fminf(wy0, __shfl_xor(wy0, off));
        wx1 = fmaxf(wx1, __shfl_xor(wx1, off));
        wy1 = fmaxf(wy1, __shfl_xor(wy1, off));
    }

    // lane l caches GT l (and its lb) in registers; candidate iff GT strictly
    // overlaps the wave bbox (touch-only => inter==0 => iou==0, safe to skip:
    // neither row-best nor column candidate since lb > 0).
    const int    l  = tid & 63;
    const float4 gl = gtb[l];
    const float  area_l = (gl.z - gl.x) * (gl.w - gl.y);  // reference op order
    const float  lbl    = lb[b * M + l];
    const bool cand = (gl.x < wx1) && (gl.z > wx0) && (gl.y < wy1) && (gl.w > wy0);
    unsigned long long mask = __ballot((int)cand);

    // best=0, bi=0: all-zero row keeps bi=0 (np argmax); strict > = first max.
    float best = 0.0f;
    int   bi   = 0;

    while (mask) {
        const int m = __builtin_amdgcn_readfirstlane(__builtin_ctzll(mask));
        mask &= mask - 1;
        // GT m fragments pulled from lane m's registers (v_readlane -> SGPR)
        const float gx0 = readlane_f(gl.x, m);
        const float gy0 = readlane_f(gl.y, m);
        const float gx1 = readlane_f(gl.z, m);
        const float gy1 = readlane_f(gl.w, m);
        const float ab  = readlane_f(area_l, m);

        float ltx = fmaxf(ax0, gx0);
        float lty = fmaxf(ay0, gy0);
        float rbx = fminf(ax1, gx1);
        float rby = fminf(ay1, gy1);
        float w = fmaxf(rbx - ltx, 0.0f);
        float h = fmaxf(rby - lty, 0.0f);
        float inter = w * h;

        if (__any(inter > 0.0f)) {
            const float lbm = readlane_f(lbl, m);
            float iou = inter / ((area_a + ab) - inter);  // IEEE div: bit-exact vs np
            if (iou > best) { best = iou; bi = m; }
            // Column candidate: iou >= lb[m] (lb <= column max by construction,
            // so this catches the argmax and all earlier ties — rare in practice).
            if (valid && iou >= lbm) {
                unsigned long long p =
                    (((unsigned long long)__float_as_uint(iou)) << 32)
                    | (unsigned int)(~(unsigned int)n);
                atomicMax(&col[b * M + m], p);
            }
        }
    }

    if (valid) {
        float cv;
        if (best < BG_T)      cv = 0.0f;
        else if (best < FG_T) cv = -1.0f;
        else                  cv = (float)(lab[b * M + bi] + 1);

        float4 g = gtb[bi];   // divergent gather, tiny table, L1-resident
        float bcx = (g.x + g.z) / 2.0f;
        float bcy = (g.y + g.w) / 2.0f;
        float bw  = g.z - g.x;
        float bh  = g.w - g.y;
        float lx = ((bcx - d.x) / d.z) / 0.1f;
        float ly = ((bcy - d.y) / d.w) / 0.1f;
        float lw = __logf(bw / d.z) / 0.2f;   // ~1e-6 abs err vs 3.54 threshold
        float lh = __logf(bh / d.w) / 0.2f;

        ((float4*)out_loc)[(size_t)b * N + n] = make_float4(lx, ly, lw, lh);
        out_cls[(size_t)b * N + n] = cv;
    }

    // ---- per-batch last-block-done fixup (best_p_idx override) ----
    // Batch b's fixup only needs batch b's col writes -> per-batch counter,
    // no grid-wide sync; fixup overlaps other batches' row work.
    __threadfence();                       // release: col atomics visible
    if (tid == 0) {
        int ret = atomicAdd(&counter[b], 1);      // device-scope by default
        s_last = (ret == (int)gridDim.x - 1);
    }
    __syncthreads();                       // block-uniform branch condition
    if (s_last) {
        __threadfence();                   // acquire: see all col writes
        if (tid < M) {
            unsigned long long p = col[b * M + tid];
            // p==0: no anchor overlapped GT tid -> np argmax of all-zero col = 0
            s_a[tid] = (p == 0ull) ? 0 : (int)(~(unsigned int)(p & 0xFFFFFFFFull));
        }
        __syncthreads();
        if (tid < M) {
            const int m = tid;
            const int a = s_a[m];
            // last-write-wins for duplicate anchors (np fancy-assignment)
            bool write = true;
            for (int mm = m + 1; mm < M; ++mm)
                if (s_a[mm] == a) { write = false; break; }
            if (write) {
                float4 dd = ((const float4*)db)[a];
                float4 g  = gtb[m];
                float bcx = (g.x + g.z) / 2.0f;
                float bcy = (g.y + g.w) / 2.0f;
                float bw  = g.z - g.x;
                float bh  = g.w - g.y;
                float lx = ((bcx - dd.x) / dd.z) / 0.1f;
                float ly = ((bcy - dd.y) / dd.w) / 0.1f;
                float lw = __logf(bw / dd.z) / 0.2f;
                float lh = __logf(bh / dd.w) / 0.2f;
                ((float4*)out_loc)[(size_t)b * N + a] = make_float4(lx, ly, lw, lh);
                out_cls[(size_t)b * N + a] = (float)(lab[b * M + m] + 1); // best_t=2.0
            }
        }
    }
}

extern "C" void kernel_launch(void* const* d_in, const int* in_sizes, int n_in,
                              void* d_out, int out_size, void* d_ws, size_t ws_size,
                              hipStream_t stream) {
    const float* gt  = (const float*)d_in[0];   // gt_boxes  [B, M, 4] xyxy
    const int*   lab = (const int*)d_in[1];     // labels    [B, M]
    const float* db  = (const float*)d_in[2];   // default_boxes [N, 4] xywh

    const int B = in_sizes[1] / M;
    const int N = in_sizes[2] / 4;

    float* out_loc = (float*)d_out;                       // [B, N, 4]
    float* out_cls = out_loc + (size_t)B * N * 4;         // [B, N]

    unsigned long long* col = (unsigned long long*)d_ws;          // [B, M] u64
    float*              lbp = (float*)(col + (size_t)B * M);      // [B, M] f32
    int*                cnt = (int*)(lbp + (size_t)B * M);        // [B]

    lb_kernel<<<dim3(B), dim3(M), 0, stream>>>(gt, db, lbp, col, cnt);
    row_kernel<<<dim3((N + 255) / 256, B), dim3(256), 0, stream>>>(
        gt, lab, db, lbp, out_loc, out_cls, col, cnt, N);
}

// Round 8
// 130.541 us; speedup vs baseline: 4.6714x; 4.6714x over previous
//
#include <hip/hip_runtime.h>

#define M 64
#define FG_T 0.6f
#define BG_T 0.4f

// packed column entry: (iou_bits << 32) | ~n — iou in (0,1] so the bit pattern
// is monotone; ties in iou resolve to SMALLER n (first occurrence = np argmax).
// 0 = "no entry"; fixup decodes p==0 -> anchor 0 (np argmax of an all-zero col).

__device__ inline float readlane_f(float v, int lane) {
    return __uint_as_float(__builtin_amdgcn_readlane(__float_as_uint(v), (unsigned)lane));
}

// -------- lb kernel: per-(b,m) lower bound on the column max + ws init ------
// For GT m, evaluate the EXACT iou (same op order as everywhere) of the 54 db
// anchors at the grid cell nearest the GT center (6 levels x 9 shapes). Each is
// a real anchor's iou -> max over them is a guaranteed lower bound on the
// column max. Also zero-inits col[b].
__global__ __launch_bounds__(64) void lb_kernel(
    const float* __restrict__ gt,    // [B, M, 4] xyxy
    const float* __restrict__ db,    // [N, 4] xywh
    float* __restrict__ lb,          // [B, M]
    unsigned long long* __restrict__ col)  // [B, M] — zero-initialized here
{
#pragma clang fp contract(off)
    const int b = blockIdx.x;
    const int m = threadIdx.x;

    col[b * M + m] = 0ull;

    const float4 g = ((const float4*)gt)[b * M + m];
    const float area_g = (g.z - g.x) * (g.w - g.y);   // reference op order
    const float gcx = (g.x + g.z) * 0.5f;
    const float gcy = (g.y + g.w) * 0.5f;

    const int   fms[6]  = {64, 32, 16, 8, 4, 2};
    const float stp[6]  = {8.0f, 16.0f, 32.0f, 64.0f, 128.0f, 256.0f};
    const int   off[6]  = {0, 36864, 46080, 48384, 48960, 49104};

    float best = 0.0f;
    #pragma unroll
    for (int i = 0; i < 6; ++i) {
        int fx = fms[i];
        int x = (int)(gcx / stp[i]); x = min(max(x, 0), fx - 1);
        int y = (int)(gcy / stp[i]); y = min(max(y, 0), fx - 1);
        int base = off[i] + (y * fx + x) * 9;
        for (int a = 0; a < 9; ++a) {
            float4 d = ((const float4*)db)[base + a];
            float ax0 = d.x - d.z / 2.0f;
            float ay0 = d.y - d.w / 2.0f;
            float ax1 = d.x + d.z / 2.0f;
            float ay1 = d.y + d.w / 2.0f;
            float area_a = (ax1 - ax0) * (ay1 - ay0);
            float ltx = fmaxf(ax0, g.x);
            float lty = fmaxf(ay0, g.y);
            float rbx = fminf(ax1, g.z);
            float rby = fminf(ay1, g.w);
            float w = fmaxf(rbx - ltx, 0.0f);
            float h = fmaxf(rby - lty, 0.0f);
            float inter = w * h;
            float iou = inter / ((area_a + area_g) - inter);  // exact anchor iou
            best = fmaxf(best, iou);
        }
    }
    lb[b * M + m] = best;
}

// ---------------- row kernel: per-anchor best GT + column candidates ----------------
__global__ __launch_bounds__(256) void row_kernel(
    const float* __restrict__ gt,    // [B, M, 4] xyxy
    const int*   __restrict__ lab,   // [B, M]
    const float* __restrict__ db,    // [N, 4] xywh
    const float* __restrict__ lb,    // [B, M] column-max lower bound
    float* __restrict__ out_loc,     // [B, N, 4]
    float* __restrict__ out_cls,     // [B, N]
    unsigned long long* __restrict__ col,  // [B, M] packed column max
    int N)
{
#pragma clang fp contract(off)
    const int b   = blockIdx.y;
    const int tid = threadIdx.x;
    const float4* __restrict__ gtb = (const float4*)gt + b * M;

    // Reverse chunk order: coarse-level anchors (high n) have whole-image wave
    // bboxes (mask ~ all 64 GTs, 5-10x work) — dispatch them FIRST so the drain
    // tail is thousands of cheap level-0 blocks, not a few heavy ones.
    const int  chunk = gridDim.x - 1 - blockIdx.x;
    const int  n     = chunk * 256 + tid;
    const bool valid = (n < N);
    const int  nl    = valid ? n : (N - 1);

    const float4 d = ((const float4*)db)[nl];
    // db_xyxy exactly as reference: c - wh/2, c + wh/2 (div by 2 is exact)
    const float ax0 = d.x - d.z / 2.0f;
    const float ay0 = d.y - d.w / 2.0f;
    const float ax1 = d.x + d.z / 2.0f;
    const float ay1 = d.y + d.w / 2.0f;
    const float area_a = (ax1 - ax0) * (ay1 - ay0);

    // one-time wave bbox (union of the wave's 64 anchors)
    float wx0 = ax0, wy0 = ay0, wx1 = ax1, wy1 = ay1;
    #pragma unroll
    for (int off = 1; off < 64; off <<= 1) {
        wx0 = fminf(wx0, __shfl_xor(wx0, off));
        wy0 = fminf(wy0, __shfl_xor(wy0, off));
        wx1 = fmaxf(wx1, __shfl_xor(wx1, off));
        wy1 = fmaxf(wy1, __shfl_xor(wy1, off));
    }

    // lane l caches GT l (and its lb) in registers; candidate iff GT strictly
    // overlaps the wave bbox (touch-only => inter==0 => iou==0, safe to skip:
    // neither row-best nor column candidate since lb > 0).
    const int    l  = tid & 63;
    const float4 gl = gtb[l];
    const float  area_l = (gl.z - gl.x) * (gl.w - gl.y);  // reference op order
    const float  lbl    = lb[b * M + l];
    const bool cand = (gl.x < wx1) && (gl.z > wx0) && (gl.y < wy1) && (gl.w > wy0);
    unsigned long long mask = __ballot((int)cand);

    // best=0, bi=0: all-zero row keeps bi=0 (np argmax); strict > = first max.
    float best = 0.0f;
    int   bi   = 0;

    while (mask) {
        const int m = __builtin_amdgcn_readfirstlane(__builtin_ctzll(mask));
        mask &= mask - 1;
        // GT m fragments pulled from lane m's registers (v_readlane -> SGPR)
        const float gx0 = readlane_f(gl.x, m);
        const float gy0 = readlane_f(gl.y, m);
        const float gx1 = readlane_f(gl.z, m);
        const float gy1 = readlane_f(gl.w, m);
        const float ab  = readlane_f(area_l, m);

        float ltx = fmaxf(ax0, gx0);
        float lty = fmaxf(ay0, gy0);
        float rbx = fminf(ax1, gx1);
        float rby = fminf(ay1, gy1);
        float w = fmaxf(rbx - ltx, 0.0f);
        float h = fmaxf(rby - lty, 0.0f);
        float inter = w * h;

        if (__any(inter > 0.0f)) {
            const float lbm = readlane_f(lbl, m);
            float iou = inter / ((area_a + ab) - inter);  // IEEE div: bit-exact vs np
            if (iou > best) { best = iou; bi = m; }
            // Column candidate: iou >= lb[m] (lb <= column max by construction,
            // so this catches the argmax and all earlier ties — rare in practice).
            if (valid && iou >= lbm) {
                unsigned long long p =
                    (((unsigned long long)__float_as_uint(iou)) << 32)
                    | (unsigned int)(~(unsigned int)n);
                atomicMax(&col[b * M + m], p);
            }
        }
    }

    if (valid) {
        float cv;
        if (best < BG_T)      cv = 0.0f;
        else if (best < FG_T) cv = -1.0f;
        else                  cv = (float)(lab[b * M + bi] + 1);

        float4 g = gtb[bi];   // divergent gather, tiny table, L1-resident
        float bcx = (g.x + g.z) / 2.0f;
        float bcy = (g.y + g.w) / 2.0f;
        float bw  = g.z - g.x;
        float bh  = g.w - g.y;
        float lx = ((bcx - d.x) / d.z) / 0.1f;
        float ly = ((bcy - d.y) / d.w) / 0.1f;
        float lw = __logf(bw / d.z) / 0.2f;   // ~1e-6 abs err vs 3.54 threshold
        float lh = __logf(bh / d.w) / 0.2f;

        ((float4*)out_loc)[(size_t)b * N + n] = make_float4(lx, ly, lw, lh);
        out_cls[(size_t)b * N + n] = cv;
    }
}

// Apply the best_p_idx override: best_t_idx[best_p[m]] = m (last write wins),
// best_t -> 2.0 so cls = lab+1 and loc re-encoded from gt[m]. Separate dispatch:
// the kernel boundary provides cross-XCD coherence for free (implicit
// writeback/invalidate) — fusing this with device-scope fences cost 4.5x (r7).
__global__ void fixup_kernel(
    const float* __restrict__ gt,
    const int*   __restrict__ lab,
    const float* __restrict__ db,
    const unsigned long long* __restrict__ col,
    float* __restrict__ out_loc,
    float* __restrict__ out_cls,
    int N)
{
#pragma clang fp contract(off)
    __shared__ int s_a[M];
    const int b = blockIdx.x;
    const int m = threadIdx.x;  // 64 threads

    unsigned long long p = col[b * M + m];
    // p==0: no anchor overlapped GT m -> np argmax of all-zero column = 0.
    int a = (p == 0ull) ? 0 : (int)(~(unsigned int)(p & 0xFFFFFFFFull));
    s_a[m] = a;
    __syncthreads();

    // last-write-wins for duplicate anchors (np fancy assignment semantics)
    bool write = true;
    for (int mm = m + 1; mm < M; ++mm) {
        if (s_a[mm] == a) { write = false; break; }
    }
    if (write) {
        float4 d = ((const float4*)db)[a];
        float4 g = ((const float4*)gt)[b * M + m];
        float bcx = (g.x + g.z) / 2.0f;
        float bcy = (g.y + g.w) / 2.0f;
        float bw  = g.z - g.x;
        float bh  = g.w - g.y;
        float lx = ((bcx - d.x) / d.z) / 0.1f;
        float ly = ((bcy - d.y) / d.w) / 0.1f;
        float lw = __logf(bw / d.z) / 0.2f;
        float lh = __logf(bh / d.w) / 0.2f;

        ((float4*)out_loc)[(size_t)b * N + a] = make_float4(lx, ly, lw, lh);
        out_cls[(size_t)b * N + a] = (float)(lab[b * M + m] + 1);  // best_t = 2.0
    }
}

extern "C" void kernel_launch(void* const* d_in, const int* in_sizes, int n_in,
                              void* d_out, int out_size, void* d_ws, size_t ws_size,
                              hipStream_t stream) {
    const float* gt  = (const float*)d_in[0];   // gt_boxes  [B, M, 4] xyxy
    const int*   lab = (const int*)d_in[1];     // labels    [B, M]
    const float* db  = (const float*)d_in[2];   // default_boxes [N, 4] xywh

    const int B = in_sizes[1] / M;
    const int N = in_sizes[2] / 4;

    float* out_loc = (float*)d_out;                       // [B, N, 4]
    float* out_cls = out_loc + (size_t)B * N * 4;         // [B, N]

    unsigned long long* col = (unsigned long long*)d_ws;          // [B, M] u64
    float*              lbp = (float*)(col + (size_t)B * M);      // [B, M] f32

    lb_kernel<<<dim3(B), dim3(M), 0, stream>>>(gt, db, lbp, col);
    row_kernel<<<dim3((N + 255) / 256, B), dim3(256), 0, stream>>>(
        gt, lab, db, lbp, out_loc, out_cls, col, N);
    fixup_kernel<<<dim3(B), dim3(M), 0, stream>>>(gt, lab, db, col, out_loc, out_cls, N);
}